// Round 13
// baseline (2430.838 us; speedup 1.0000x reference)
//
#include <hip/hip_runtime.h>
#include <hip/hip_bf16.h>

#define NL   6
#define NH   16
#define HID  1024
#define HD   64
#define FFW  4096
#define VOC  32000
#define WINN 512
#define EMB  128
#define NB   4
#define TT   1024   // WIN + WIN

typedef __attribute__((ext_vector_type(8))) _Float16 f16x8;
typedef __attribute__((ext_vector_type(8))) short    b16x8;
typedef __attribute__((ext_vector_type(4))) float    f32x4;

__device__ __forceinline__ ushort f2b(float f) {
    __hip_bfloat16 h = __float2bfloat16(f);
    return *reinterpret_cast<ushort*>(&h);
}
// split f32 into fp16 hi/lo:  f ~= hi + lo * 2^-11  (error ~ |f|*2^-22)
__device__ __forceinline__ void split16(float f, ushort& hb, ushort& lb) {
    _Float16 h = (_Float16)f;
    _Float16 l = (_Float16)((f - (float)h) * 2048.0f);
    hb = __builtin_bit_cast(ushort, h);
    lb = __builtin_bit_cast(ushort, l);
}
// async global->LDS, 16B per lane: LDS dest = (wave-uniform base) + lane*16
__device__ __forceinline__ void gload16(const void* g, void* l) {
    __builtin_amdgcn_global_load_lds(
        (const __attribute__((address_space(1))) unsigned int*)g,
        (__attribute__((address_space(3))) unsigned int*)l, 16, 0, 0);
}

// ---------------------------------------------------------------------------
// Embed (f32)
// ---------------------------------------------------------------------------
__global__ __launch_bounds__(256) void embed_kernel(
    const int* __restrict__ xin, const float* __restrict__ Wemb,
    const float* __restrict__ Wlin, float* __restrict__ h0)
{
    int row = blockIdx.x;
    int tok = xin[row];
    __shared__ float tk[EMB];
    if (threadIdx.x < EMB) tk[threadIdx.x] = Wemb[tok * EMB + threadIdx.x] * 0.03125f;
    __syncthreads();
    for (int j = 0; j < 4; ++j) {
        int c = threadIdx.x + 256 * j;
        float acc = 0.f;
        for (int e = 0; e < EMB; ++e) acc += tk[e] * Wlin[e * HID + c];
        h0[(long)row * HID + c] = acc;
    }
}

// ---------------------------------------------------------------------------
// x = pos + concat(prev, cur); outputs f32 + fp16 hi/lo split
// ---------------------------------------------------------------------------
__global__ __launch_bounds__(256) void build_x_kernel(
    const float* __restrict__ pos, const float* __restrict__ prev,
    const float* __restrict__ cur, float* __restrict__ x,
    ushort* __restrict__ xh, ushort* __restrict__ xl)
{
    int i4 = blockIdx.x * blockDim.x + threadIdx.x;
    if (i4 >= NB * TT * HID / 4) return;
    int h4 = i4 % (HID / 4);
    int bt = i4 / (HID / 4);
    int t = bt % TT, b = bt / TT;
    float4 p = ((const float4*)pos)[t * (HID / 4) + h4];
    float4 s;
    if (t < WINN) s = ((const float4*)prev)[(long)(b * WINN + t) * (HID / 4) + h4];
    else          s = ((const float4*)cur)[(long)(b * WINN + (t - WINN)) * (HID / 4) + h4];
    float4 r; r.x = p.x + s.x; r.y = p.y + s.y; r.z = p.z + s.z; r.w = p.w + s.w;
    ((float4*)x)[i4] = r;
    ushort4 uh, ul;
    split16(r.x, uh.x, ul.x); split16(r.y, uh.y, ul.y);
    split16(r.z, uh.z, ul.z); split16(r.w, uh.w, ul.w);
    ((ushort4*)xh)[i4] = uh;
    ((ushort4*)xl)[i4] = ul;
}

// ---------------------------------------------------------------------------
// Fused QKVC weight split: z picks {Q,K,V,C}; all 1024x1024.
// ---------------------------------------------------------------------------
__global__ __launch_bounds__(256) void wsplit4_kernel(
    const float* __restrict__ pq, const float* __restrict__ pk,
    const float* __restrict__ pv, const float* __restrict__ pc,
    ushort* __restrict__ wq_h, ushort* __restrict__ wq_l,
    ushort* __restrict__ wkv_h, ushort* __restrict__ wkv_l,
    ushort* __restrict__ wc_h, ushort* __restrict__ wc_l)
{
    const float* src; ushort* dh; ushort* dl;
    switch (blockIdx.z) {
        case 0:  src = pq; dh = wq_h;            dl = wq_l;            break;
        case 1:  src = pk; dh = wkv_h;           dl = wkv_l;           break;
        case 2:  src = pv; dh = wkv_h + 1048576; dl = wkv_l + 1048576; break;
        default: src = pc; dh = wc_h;            dl = wc_l;            break;
    }
    __shared__ float ts[32][33];
    int n0 = blockIdx.x * 32, k0 = blockIdx.y * 32;
    int tr = threadIdx.x >> 5, tc = threadIdx.x & 31;
#pragma unroll
    for (int j = 0; j < 4; ++j)
        ts[tr + j * 8][tc] = src[(long)(k0 + tr + j * 8) * HID + n0 + tc];
    __syncthreads();
#pragma unroll
    for (int j = 0; j < 4; ++j) {
        int n = tr + j * 8;
        ushort hb, lb;
        split16(ts[tc][n], hb, lb);
        long idx = (long)(n0 + n) * HID + k0 + tc;
        dh[idx] = hb;
        dl[idx] = lb;
    }
}

// ---------------------------------------------------------------------------
// Fused FF1+FF2 weight split. grid (128, 32, 2).
// z=0: pf1 [HID,FFW] -> f1 [FFW,HID]; n0=bx*32, k0=by*32
// z=1: pf2 [FFW,HID] -> f2 [HID,FFW]; n0=by*32, k0=bx*32
// ---------------------------------------------------------------------------
__global__ __launch_bounds__(256) void wsplitff_kernel(
    const float* __restrict__ pf1, const float* __restrict__ pf2,
    ushort* __restrict__ f1h, ushort* __restrict__ f1l,
    ushort* __restrict__ f2h, ushort* __restrict__ f2l)
{
    const float* W; ushort* dh; ushort* dl; int K, N, n0, k0;
    if (blockIdx.z == 0) {
        W = pf1; dh = f1h; dl = f1l; K = HID; N = FFW;
        n0 = blockIdx.x * 32; k0 = blockIdx.y * 32;
    } else {
        W = pf2; dh = f2h; dl = f2l; K = FFW; N = HID;
        n0 = blockIdx.y * 32; k0 = blockIdx.x * 32;
    }
    __shared__ float ts[32][33];
    int tr = threadIdx.x >> 5, tc = threadIdx.x & 31;
#pragma unroll
    for (int j = 0; j < 4; ++j)
        ts[tr + j * 8][tc] = W[(long)(k0 + tr + j * 8) * N + n0 + tc];
    __syncthreads();
#pragma unroll
    for (int j = 0; j < 4; ++j) {
        int n = tr + j * 8;
        ushort hb, lb;
        split16(ts[tc][n], hb, lb);
        long idx = (long)(n0 + n) * K + k0 + tc;
        dh[idx] = hb;
        dl[idx] = lb;
    }
}

// ---------------------------------------------------------------------------
// ushort-pair transpose with source row stride
// ---------------------------------------------------------------------------
__global__ __launch_bounds__(256) void vtrans_kernel(
    const ushort* __restrict__ vh, const ushort* __restrict__ vl,
    ushort* __restrict__ vth, ushort* __restrict__ vtl, int src_stride)
{
    __shared__ ushort th[32][33], tl[32][33];
    int n0 = blockIdx.x * 32, r0 = blockIdx.y * 32;
    int tr = threadIdx.x >> 5, tc = threadIdx.x & 31;
#pragma unroll
    for (int j = 0; j < 4; ++j) {
        long g = (long)(r0 + tr + j * 8) * src_stride + n0 + tc;
        th[tr + j * 8][tc] = vh[g];
        tl[tr + j * 8][tc] = vl[g];
    }
    __syncthreads();
#pragma unroll
    for (int j = 0; j < 4; ++j) {
        long g = (long)(n0 + tr + j * 8) * (NB * TT) + r0 + tc;
        vth[g] = th[tc][tr + j * 8];
        vtl[g] = tl[tc][tr + j * 8];
    }
}

// ---------------------------------------------------------------------------
// Unified split-fp16 MFMA GEMM: 128x128 tile, 8 waves (2x4), wave = 64x32,
// BK=32, global_load_lds staging, linear LDS. gridDim.z split-K (k_off=z*Ksub).
// f32 mode (Cf0 != null): block z writes Cf[z], bias only on z==0.
// fp16-split mode: writes Chh/Cll. amap remaps A rows.
// ---------------------------------------------------------------------------
__global__ __launch_bounds__(512) void hgemm8(
    const ushort* __restrict__ Ah, const ushort* __restrict__ Al,
    const ushort* __restrict__ Bh, const ushort* __restrict__ Bl,
    ushort* __restrict__ Chh, ushort* __restrict__ Cll,
    float* __restrict__ Cf0, float* __restrict__ Cf1,
    float* __restrict__ Cf2, float* __restrict__ Cf3,
    int M, int N, int K_stride, int Ksub,
    float scale, const float* __restrict__ bias, int relu, int amap)
{
    __shared__ __align__(16) ushort Ash[128 * 32];
    __shared__ __align__(16) ushort Asl[128 * 32];
    __shared__ __align__(16) ushort Bsh[128 * 32];
    __shared__ __align__(16) ushort Bsl[128 * 32];
    const int tid  = threadIdx.x;
    const int rb   = blockIdx.y * 128;
    const int cb   = blockIdx.x * 128;
    const int z    = blockIdx.z;
    const int k_off = z * Ksub;
    const int wave = tid >> 6, lane = tid & 63;
    const int wr   = (wave >> 2) * 64;
    const int wc   = (wave & 3) * 32;
    const int lr   = lane & 15;
    const int kh   = lane >> 4;

    const int lrow = lane >> 2;
    const int lkc  = (lane & 3) * 8;
    int gra = rb + wave * 16 + lrow;
    long marow = amap ? (long)((gra >> 9) * 1024 + 512 + (gra & 511)) : (long)gra;
    const ushort* gA_h = Ah + marow * K_stride + k_off + lkc;
    const ushort* gA_l = Al + marow * K_stride + k_off + lkc;
    const ushort* gB_h = Bh + (long)(cb + wave * 16 + lrow) * K_stride + k_off + lkc;
    const ushort* gB_l = Bl + (long)(cb + wave * 16 + lrow) * K_stride + k_off + lkc;
    ushort* lA_h = Ash + wave * 512;
    ushort* lA_l = Asl + wave * 512;
    ushort* lB_h = Bsh + wave * 512;
    ushort* lB_l = Bsl + wave * 512;

    int aoff[4], boff[2];
#pragma unroll
    for (int m = 0; m < 4; ++m) aoff[m] = (wr + m * 16 + lr) * 32 + kh * 8;
#pragma unroll
    for (int n = 0; n < 2; ++n) boff[n] = (wc + n * 16 + lr) * 32 + kh * 8;

    f32x4 accH[4][2], accL[4][2];
#pragma unroll
    for (int m = 0; m < 4; ++m)
#pragma unroll
        for (int n = 0; n < 2; ++n) {
            accH[m][n] = (f32x4){0.f, 0.f, 0.f, 0.f};
            accL[m][n] = (f32x4){0.f, 0.f, 0.f, 0.f};
        }

    for (int k0 = 0; k0 < Ksub; k0 += 32) {
        __syncthreads();
        gload16(gA_h + k0, lA_h);
        gload16(gA_l + k0, lA_l);
        gload16(gB_h + k0, lB_h);
        gload16(gB_l + k0, lB_l);
        __syncthreads();
        f16x8 afh[4], afl[4], bfh[2], bfl[2];
#pragma unroll
        for (int m = 0; m < 4; ++m) {
            afh[m] = *(const f16x8*)(Ash + aoff[m]);
            afl[m] = *(const f16x8*)(Asl + aoff[m]);
        }
#pragma unroll
        for (int n = 0; n < 2; ++n) {
            bfh[n] = *(const f16x8*)(Bsh + boff[n]);
            bfl[n] = *(const f16x8*)(Bsl + boff[n]);
        }
#pragma unroll
        for (int m = 0; m < 4; ++m)
#pragma unroll
            for (int n = 0; n < 2; ++n) {
                accH[m][n] = __builtin_amdgcn_mfma_f32_16x16x32_f16(afh[m], bfh[n], accH[m][n], 0, 0, 0);
                accL[m][n] = __builtin_amdgcn_mfma_f32_16x16x32_f16(afh[m], bfl[n], accL[m][n], 0, 0, 0);
                accL[m][n] = __builtin_amdgcn_mfma_f32_16x16x32_f16(afl[m], bfh[n], accL[m][n], 0, 0, 0);
            }
    }

    if (Cf0) {
        float* __restrict__ Cf = (z == 0) ? Cf0 : (z == 1) ? Cf1 : (z == 2) ? Cf2 : Cf3;
        const float* bias_eff = (z == 0) ? bias : nullptr;
#pragma unroll
        for (int m = 0; m < 4; ++m) {
            int row0 = rb + wr + m * 16 + kh * 4;
#pragma unroll
            for (int n = 0; n < 2; ++n) {
                int col = cb + wc + n * 16 + lr;
                float bv = bias_eff ? bias_eff[col] : 0.f;
#pragma unroll
                for (int r = 0; r < 4; ++r) {
                    float v = (accH[m][n][r] + accL[m][n][r] * (1.f / 2048.f)) * scale + bv;
                    if (relu) v = fmaxf(v, 0.f);
                    Cf[(long)(row0 + r) * N + col] = v;
                }
            }
        }
    } else {
#pragma unroll
        for (int m = 0; m < 4; ++m) {
            int row0 = rb + wr + m * 16 + kh * 4;
#pragma unroll
            for (int n = 0; n < 2; ++n) {
                int col = cb + wc + n * 16 + lr;
                float bv = bias ? bias[col] : 0.f;
#pragma unroll
                for (int r = 0; r < 4; ++r) {
                    float v = (accH[m][n][r] + accL[m][n][r] * (1.f / 2048.f)) * scale + bv;
                    if (relu) v = fmaxf(v, 0.f);
                    long idx = (long)(row0 + r) * N + col;
                    ushort hb, lb; split16(v, hb, lb);
                    Chh[idx] = hb; Cll[idx] = lb;
                }
            }
        }
    }
}

// ---------------------------------------------------------------------------
// MFMA flash attention. Scores arrive in base-2 domain (Q pre-scaled by
// 0.125*log2e), softmax uses native exp2f. T13 defer-max (THR=11, P<=2048),
// T14 async-STAGE, T5 setprio around MFMA clusters.
// Q = qa+qb+qc+qd (f32 split-K partials).
// ---------------------------------------------------------------------------
#define RTHR 11.0f
__global__ __launch_bounds__(256) void fattn_mfma(
    const float* __restrict__ qa, const float* __restrict__ qb,
    const float* __restrict__ qc, const float* __restrict__ qd,
    const ushort* __restrict__ kbh, const ushort* __restrict__ kbl, int kstr,
    const ushort* __restrict__ vth, const ushort* __restrict__ vtl,
    ushort* __restrict__ oh, ushort* __restrict__ ol)
{
    __shared__ __align__(16) ushort ksh[64 * 72];
    __shared__ __align__(16) ushort ksl[64 * 72];
    __shared__ __align__(16) ushort vsh[64 * 72];
    __shared__ __align__(16) ushort vsl[64 * 72];
    const int qt = blockIdx.x, h = blockIdx.y, b = blockIdx.z;
    const int tid = threadIdx.x;
    const int wave = tid >> 6, lane = tid & 63;
    const int lr = lane & 15, kg4 = lane >> 4;
    const int qbase = b * WINN + qt * 64;

    f16x8 qfh[2], qfl[2];
#pragma unroll
    for (int c = 0; c < 2; ++c) {
        long ga = (long)(qbase + wave * 16 + lr) * HID + h * HD + c * 32 + kg4 * 8;
        float4 a0 = *(const float4*)(qa + ga);
        float4 a1 = *(const float4*)(qa + ga + 4);
        float4 b0 = *(const float4*)(qb + ga);
        float4 b1 = *(const float4*)(qb + ga + 4);
        float4 c0 = *(const float4*)(qc + ga);
        float4 c1 = *(const float4*)(qc + ga + 4);
        float4 d0 = *(const float4*)(qd + ga);
        float4 d1 = *(const float4*)(qd + ga + 4);
        float qv[8] = {a0.x + b0.x + c0.x + d0.x, a0.y + b0.y + c0.y + d0.y,
                       a0.z + b0.z + c0.z + d0.z, a0.w + b0.w + c0.w + d0.w,
                       a1.x + b1.x + c1.x + d1.x, a1.y + b1.y + c1.y + d1.y,
                       a1.z + b1.z + c1.z + d1.z, a1.w + b1.w + c1.w + d1.w};
        ushort uh[8], ul[8];
#pragma unroll
        for (int j = 0; j < 8; ++j) split16(qv[j], uh[j], ul[j]);
        qfh[c] = *(const f16x8*)uh;
        qfl[c] = *(const f16x8*)ul;
    }

    f32x4 accOH[4], accOL[4];
#pragma unroll
    for (int d = 0; d < 4; ++d) {
        accOH[d] = (f32x4){0.f, 0.f, 0.f, 0.f};
        accOL[d] = (f32x4){0.f, 0.f, 0.f, 0.f};
    }
    float mrow[4], lrow[4];
#pragma unroll
    for (int r = 0; r < 4; ++r) { mrow[r] = -3.0e38f; lrow[r] = 0.f; }

    const int sr = tid >> 2;
    const int sd = (tid & 3) * 16;

    uint4 rk0, rk1, rk2, rk3, rv0, rv1, rv2, rv3;
    {   // prologue: tile 0 -> regs
        long gk = (long)(b * TT + sr) * kstr + h * HD + sd;
        rk0 = *(const uint4*)(kbh + gk); rk1 = *(const uint4*)(kbh + gk + 8);
        rk2 = *(const uint4*)(kbl + gk); rk3 = *(const uint4*)(kbl + gk + 8);
        long gv = (long)(h * HD + sr) * (NB * TT) + b * TT + sd;
        rv0 = *(const uint4*)(vth + gv); rv1 = *(const uint4*)(vth + gv + 8);
        rv2 = *(const uint4*)(vtl + gv); rv3 = *(const uint4*)(vtl + gv + 8);
    }

    const int ktmax = 9 + qt;
    for (int kt = 0; kt < ktmax; ++kt) {
        __syncthreads();
        *(uint4*)(ksh + sr * 72 + sd) = rk0;
        *(uint4*)(ksh + sr * 72 + sd + 8) = rk1;
        *(uint4*)(ksl + sr * 72 + sd) = rk2;
        *(uint4*)(ksl + sr * 72 + sd + 8) = rk3;
        *(uint4*)(vsh + sr * 72 + sd) = rv0;
        *(uint4*)(vsh + sr * 72 + sd + 8) = rv1;
        *(uint4*)(vsl + sr * 72 + sd) = rv2;
        *(uint4*)(vsl + sr * 72 + sd + 8) = rv3;
        __syncthreads();

        f32x4 sH[4], sL[4];
#pragma unroll
        for (int n = 0; n < 4; ++n) {
            sH[n] = (f32x4){0.f, 0.f, 0.f, 0.f};
            sL[n] = (f32x4){0.f, 0.f, 0.f, 0.f};
        }
        __builtin_amdgcn_s_setprio(1);
#pragma unroll
        for (int c = 0; c < 2; ++c) {
#pragma unroll
            for (int n = 0; n < 4; ++n) {
                int ad = (n * 16 + lr) * 72 + c * 32 + kg4 * 8;
                f16x8 bh = *(const f16x8*)(ksh + ad);
                f16x8 bl = *(const f16x8*)(ksl + ad);
                sH[n] = __builtin_amdgcn_mfma_f32_16x16x32_f16(qfh[c], bh, sH[n], 0, 0, 0);
                sL[n] = __builtin_amdgcn_mfma_f32_16x16x32_f16(qfh[c], bl, sL[n], 0, 0, 0);
                sL[n] = __builtin_amdgcn_mfma_f32_16x16x32_f16(qfl[c], bh, sL[n], 0, 0, 0);
            }
        }
        __builtin_amdgcn_s_setprio(0);

        // T14: next tile's global loads issue here; latency hides under
        // softmax + PV.
        if (kt + 1 < ktmax) {
            long gk = (long)(b * TT + (kt + 1) * 64 + sr) * kstr + h * HD + sd;
            rk0 = *(const uint4*)(kbh + gk); rk1 = *(const uint4*)(kbh + gk + 8);
            rk2 = *(const uint4*)(kbl + gk); rk3 = *(const uint4*)(kbl + gk + 8);
            long gv = (long)(h * HD + sr) * (NB * TT) + b * TT + (kt + 1) * 64 + sd;
            rv0 = *(const uint4*)(vth + gv); rv1 = *(const uint4*)(vth + gv + 8);
            rv2 = *(const uint4*)(vtl + gv); rv3 = *(const uint4*)(vtl + gv + 8);
        }

        float S[4][4];
#pragma unroll
        for (int n = 0; n < 4; ++n)
#pragma unroll
            for (int r = 0; r < 4; ++r)
                S[n][r] = sH[n][r] + sL[n][r] * (1.f / 2048.f);

        if (kt == ktmax - 1) {
#pragma unroll
            for (int r = 0; r < 4; ++r) {
                int qi = WINN + qt * 64 + wave * 16 + kg4 * 4 + r;
#pragma unroll
                for (int n = 0; n < 4; ++n) {
                    int kg = kt * 64 + n * 16 + lr;
                    if (kg > qi) S[n][r] = -1e9f;
                }
            }
        }

        // online softmax, base-2 domain, T13 defer-max
        float mx[4];
#pragma unroll
        for (int r = 0; r < 4; ++r) {
            float m0 = fmaxf(fmaxf(S[0][r], S[1][r]), fmaxf(S[2][r], S[3][r]));
            m0 = fmaxf(m0, __shfl_xor(m0, 1));
            m0 = fmaxf(m0, __shfl_xor(m0, 2));
            m0 = fmaxf(m0, __shfl_xor(m0, 4));
            m0 = fmaxf(m0, __shfl_xor(m0, 8));
            mx[r] = m0;
        }
        bool need = (mx[0] > mrow[0] + RTHR) || (mx[1] > mrow[1] + RTHR) ||
                    (mx[2] > mrow[2] + RTHR) || (mx[3] > mrow[3] + RTHR);
        if (__ballot(need)) {   // wave-uniform branch
#pragma unroll
            for (int r = 0; r < 4; ++r) {
                float mnew = fmaxf(mrow[r], mx[r]);
                float alpha = exp2f(mrow[r] - mnew);
                lrow[r] *= alpha;
                mrow[r] = mnew;
#pragma unroll
                for (int d = 0; d < 4; ++d) { accOH[d][r] *= alpha; accOL[d][r] *= alpha; }
            }
        }
#pragma unroll
        for (int r = 0; r < 4; ++r) {
            float rs = 0.f;
#pragma unroll
            for (int n = 0; n < 4; ++n) { S[n][r] = exp2f(S[n][r] - mrow[r]); rs += S[n][r]; }
            rs += __shfl_xor(rs, 1);
            rs += __shfl_xor(rs, 2);
            rs += __shfl_xor(rs, 4);
            rs += __shfl_xor(rs, 8);
            lrow[r] += rs;
        }

        __syncthreads();
#pragma unroll
        for (int n = 0; n < 4; ++n)
#pragma unroll
            for (int r = 0; r < 4; ++r) {
                ushort hb, lb;
                split16(S[n][r], hb, lb);
                int ad = (wave * 16 + kg4 * 4 + r) * 72 + n * 16 + lr;
                ksh[ad] = hb;
                ksl[ad] = lb;
            }
        f16x8 pfh[2], pfl[2];
#pragma unroll
        for (int c = 0; c < 2; ++c) {
            int ad = (wave * 16 + lr) * 72 + c * 32 + kg4 * 8;
            pfh[c] = *(const f16x8*)(ksh + ad);
            pfl[c] = *(const f16x8*)(ksl + ad);
        }
        __builtin_amdgcn_s_setprio(1);
#pragma unroll
        for (int c = 0; c < 2; ++c) {
#pragma unroll
            for (int d = 0; d < 4; ++d) {
                int ad = (d * 16 + lr) * 72 + c * 32 + kg4 * 8;
                f16x8 vh = *(const f16x8*)(vsh + ad);
                f16x8 vl = *(const f16x8*)(vsl + ad);
                accOH[d] = __builtin_amdgcn_mfma_f32_16x16x32_f16(pfh[c], vh, accOH[d], 0, 0, 0);
                accOL[d] = __builtin_amdgcn_mfma_f32_16x16x32_f16(pfh[c], vl, accOL[d], 0, 0, 0);
                accOL[d] = __builtin_amdgcn_mfma_f32_16x16x32_f16(pfl[c], vh, accOL[d], 0, 0, 0);
            }
        }
        __builtin_amdgcn_s_setprio(0);
    }

#pragma unroll
    for (int r = 0; r < 4; ++r) {
        float inv = 1.f / lrow[r];
        long rowb = (long)(qbase + wave * 16 + kg4 * 4 + r) * HID + h * HD + lr;
#pragma unroll
        for (int d = 0; d < 4; ++d) {
            float v = (accOH[d][r] + accOL[d][r] * (1.f / 2048.f)) * inv;
            ushort hb, lb;
            split16(v, hb, lb);
            oh[rowb + d * 16] = hb;
            ol[rowb + d * 16] = lb;
        }
    }
}

// ---------------------------------------------------------------------------
// Transpose+convert (bf16, logits W)
// ---------------------------------------------------------------------------
__global__ __launch_bounds__(256) void transp_kernel(
    const float* __restrict__ W, ushort* __restrict__ Wt, int K, int N)
{
    __shared__ float ts[32][33];
    int n0 = blockIdx.x * 32, k0 = blockIdx.y * 32;
    int tr = threadIdx.x >> 5, tc = threadIdx.x & 31;
#pragma unroll
    for (int j = 0; j < 4; ++j)
        ts[tr + j * 8][tc] = W[(long)(k0 + tr + j * 8) * N + n0 + tc];
    __syncthreads();
#pragma unroll
    for (int j = 0; j < 4; ++j) {
        int n = tr + j * 8;
        Wt[(long)(n0 + n) * K + k0 + tc] = f2b(ts[tc][n]);
    }
}

// ---------------------------------------------------------------------------
// bf16 MFMA GEMM (logits). B-reuse-ordered XCD swizzle + global_load_lds.
// ---------------------------------------------------------------------------
__global__ __launch_bounds__(256) void mfma_gemm(
    const ushort* __restrict__ A, const ushort* __restrict__ Bt,
    float* __restrict__ Cf, int M, int N, int K)
{
    __shared__ __align__(16) ushort As[128 * 32];
    __shared__ __align__(16) ushort Bs[128 * 32];
    const int tid  = threadIdx.x;
    const int ntm  = M >> 7;
    const int nbx  = gridDim.x;
    const int nwg  = nbx * gridDim.y;
    const int bid  = blockIdx.y * nbx + blockIdx.x;
    const int cpx  = nwg >> 3;
    const int swz  = (bid & 7) * cpx + (bid >> 3);
    const int rb   = (swz % ntm) * 128;
    const int cb   = (swz / ntm) * 128;
    const int wave = tid >> 6, lane = tid & 63;
    const int wr   = (wave >> 1) * 64;
    const int wc   = (wave & 1) * 64;
    const int lr   = lane & 15;
    const int kh   = lane >> 4;

    const int lrow = lane >> 2;
    const int lkc  = (lane & 3) * 8;
    const ushort* gA0 = A + (long)(rb + wave * 32 + lrow) * K + lkc;
    const ushort* gA1 = A + (long)(rb + wave * 32 + 16 + lrow) * K + lkc;
    const ushort* gB0 = Bt + (long)(cb + wave * 32 + lrow) * K + lkc;
    const ushort* gB1 = Bt + (long)(cb + wave * 32 + 16 + lrow) * K + lkc;
    ushort* lA0 = As + wave * 1024;
    ushort* lA1 = As + wave * 1024 + 512;
    ushort* lB0 = Bs + wave * 1024;
    ushort* lB1 = Bs + wave * 1024 + 512;

    int aoff[4], boff[4];
#pragma unroll
    for (int m = 0; m < 4; ++m) aoff[m] = (wr + m * 16 + lr) * 32 + kh * 8;
#pragma unroll
    for (int n = 0; n < 4; ++n) boff[n] = (wc + n * 16 + lr) * 32 + kh * 8;

    f32x4 acc[4][4];
#pragma unroll
    for (int m = 0; m < 4; ++m)
#pragma unroll
        for (int n = 0; n < 4; ++n)
            acc[m][n] = (f32x4){0.f, 0.f, 0.f, 0.f};

    for (int k0 = 0; k0 < K; k0 += 32) {
        __syncthreads();
        gload16(gA0 + k0, lA0);
        gload16(gA1 + k0, lA1);
        gload16(gB0 + k0, lB0);
        gload16(gB1 + k0, lB1);
        __syncthreads();
        b16x8 af[4], bfr[4];
#pragma unroll
        for (int m = 0; m < 4; ++m) af[m] = *(const b16x8*)(As + aoff[m]);
#pragma unroll
        for (int n = 0; n < 4; ++n) bfr[n] = *(const b16x8*)(Bs + boff[n]);
#pragma unroll
        for (int m = 0; m < 4; ++m)
#pragma unroll
            for (int n = 0; n < 4; ++n)
                acc[m][n] = __builtin_amdgcn_mfma_f32_16x16x32_bf16(af[m], bfr[n], acc[m][n], 0, 0, 0);
    }

#pragma unroll
    for (int m = 0; m < 4; ++m) {
        int row0 = rb + wr + m * 16 + kh * 4;
#pragma unroll
        for (int n = 0; n < 4; ++n) {
            int col = cb + wc + n * 16 + lr;
#pragma unroll
            for (int r = 0; r < 4; ++r)
                Cf[(long)(row0 + r) * N + col] = acc[m][n][r];
        }
    }
}

// ---------------------------------------------------------------------------
// out = res[r'] + LN(t + t2 + t3 + t4)*scale + bias (t2..t4 optional);
// outputs f32 / fp16-split / bf16 mirrors.
// ---------------------------------------------------------------------------
__global__ __launch_bounds__(256) void ln_res_kernel(
    const float* __restrict__ t, const float* __restrict__ t2,
    const float* __restrict__ t3, const float* __restrict__ t4,
    const float* __restrict__ res, float* __restrict__ out,
    ushort* __restrict__ outh, ushort* __restrict__ outl, ushort* __restrict__ outb,
    const float* __restrict__ bias, const float* __restrict__ scale, int res_map)
{
    int r = blockIdx.x;
    int tid = threadIdx.x;
    long rr = res_map ? (long)((r >> 9) * 1024 + 512 + (r & 511)) : (long)r;
    float4 v = ((const float4*)(t + (long)r * HID))[tid];
    if (t2) {
        float4 w = ((const float4*)(t2 + (long)r * HID))[tid];
        v.x += w.x; v.y += w.y; v.z += w.z; v.w += w.w;
    }
    if (t3) {
        float4 w = ((const float4*)(t3 + (long)r * HID))[tid];
        v.x += w.x; v.y += w.y; v.z += w.z; v.w += w.w;
    }
    if (t4) {
        float4 w = ((const float4*)(t4 + (long)r * HID))[tid];
        v.x += w.x; v.y += w.y; v.z += w.z; v.w += w.w;
    }
    __shared__ float red[4];
    float s = v.x + v.y + v.z + v.w;
    for (int off = 32; off > 0; off >>= 1) s += __shfl_xor(s, off);
    if ((tid & 63) == 0) red[tid >> 6] = s;
    __syncthreads();
    float mean = (red[0] + red[1] + red[2] + red[3]) * (1.f / HID);
    __syncthreads();
    float dx = v.x - mean, dy = v.y - mean, dz = v.z - mean, dw = v.w - mean;
    float qs = dx * dx + dy * dy + dz * dz + dw * dw;
    for (int off = 32; off > 0; off >>= 1) qs += __shfl_xor(qs, off);
    if ((tid & 63) == 0) red[tid >> 6] = qs;
    __syncthreads();
    float var = (red[0] + red[1] + red[2] + red[3]) * (1.f / HID);
    float rs = rsqrtf(var + 1e-6f);
    float4 rv = ((const float4*)(res + rr * HID))[tid];
    float4 sc4 = ((const float4*)scale)[tid];
    float4 b4  = ((const float4*)bias)[tid];
    float4 o4;
    o4.x = rv.x + dx * rs * sc4.x + b4.x;
    o4.y = rv.y + dy * rs * sc4.y + b4.y;
    o4.z = rv.z + dz * rs * sc4.z + b4.z;
    o4.w = rv.w + dw * rs * sc4.w + b4.w;
    ((float4*)(out + (long)r * HID))[tid] = o4;
    if (outh) {
        ushort4 uh, ul;
        split16(o4.x, uh.x, ul.x); split16(o4.y, uh.y, ul.y);
        split16(o4.z, uh.z, ul.z); split16(o4.w, uh.w, ul.w);
        ((ushort4*)(outh + (long)r * HID))[tid] = uh;
        ((ushort4*)(outl + (long)r * HID))[tid] = ul;
    }
    if (outb) {
        ushort4 u; u.x = f2b(o4.x); u.y = f2b(o4.y); u.z = f2b(o4.z); u.w = f2b(o4.w);
        ((ushort4*)(outb + (long)r * HID))[tid] = u;
    }
}

// ---------------------------------------------------------------------------
// Workspace (168 MiB, proven safe). Overlays as R12.
// ---------------------------------------------------------------------------
extern "C" void kernel_launch(void* const* d_in, const int* in_sizes, int n_in,
                              void* d_out, int out_size, void* d_ws, size_t ws_size,
                              hipStream_t stream)
{
    const int*   x_input = (const int*)  d_in[0];
    const float* prev    = (const float*)d_in[1];
    const float* Wemb    = (const float*)d_in[2];
    const float* Wlin    = (const float*)d_in[3];
    const float* pdec    = (const float*)d_in[4];
    const float* pq      = (const float*)d_in[5];
    const float* pk      = (const float*)d_in[6];
    const float* pv      = (const float*)d_in[7];
    const float* pc      = (const float*)d_in[8];
    const float* pf1     = (const float*)d_in[9];
    const float* pf2     = (const float*)d_in[10];
    const float* bf1     = (const float*)d_in[11];
    const float* bf2     = (const float*)d_in[12];
    const float* b1      = (const float*)d_in[13];
    const float* b2      = (const float*)d_in[14];
    const float* s1      = (const float*)d_in[15];
    const float* s2      = (const float*)d_in[16];
    const float* pos     = (const float*)d_in[17];

    float* outp   = (float*)d_out;
    float* logits = outp;
    float* dec    = outp + (long)2048 * VOC;

    char* base = (char*)d_ws;
    float*  x_f   = (float*) (base + 0);
    ushort* x_hi  = (ushort*)(base + 16777216);
    ushort* x_lo  = (ushort*)(base + 25165824);
    ushort* kv_hi = (ushort*)(base + 33554432);
    ushort* kv_lo = (ushort*)(base + 50331648);
    ushort* vt_hi = (ushort*)(base + 67108864);
    ushort* vt_lo = (ushort*)(base + 75497472);
    ushort* o_hi  = (ushort*)(base + 83886080);
    ushort* o_lo  = (ushort*)(base + 88080384);
    float*  t0a   = (float*) (base + 92274688);
    float*  h0    = t0a;
    float*  qa    = t0a;
    float*  t0b   = (float*) (base + 100663296);
    float*  qb    = t0b;
    float*  xs    = (float*) (base + 109051904);
    ushort* xs_hi = (ushort*)(base + 117440512);
    ushort* xs_lo = (ushort*)(base + 121634816);
    ushort* wq_hi = (ushort*)(base + 125829120);
    ushort* wq_lo = (ushort*)(base + 127926272);
    ushort* wkv_hi= (ushort*)(base + 130023424);
    ushort* wkv_lo= (ushort*)(base + 134217728);
    ushort* wc_hi = (ushort*)(base + 138412032);
    ushort* wc_lo = (ushort*)(base + 140509184);
    ushort* wf1_hi= (ushort*)(base + 142606336);
    ushort* wf1_lo= (ushort*)(base + 150994944);
    ushort* wf2_hi= (ushort*)(base + 159383552);
    ushort* wf2_lo= (ushort*)(base + 167772160);   // ends 176,160,768
    // overlays
    float*  t0c   = (float*) (base + 67108864);    // vt_hi region (post-fattn)
    float*  t0d   = (float*) (base + 75497472);    // vt_lo region (post-fattn)
    float*  qc    = (float*) (base + 109051904);   // xs region (pre-ln1)
    float*  qd    = (float*) (base + 117440512);   // xs_hi+xs_lo region (pre-ln1)
    ushort* ff1_hi= (ushort*)(base + 33554432);
    ushort* ff1_lo= (ushort*)(base + 50331648);
    ushort* decb  = (ushort*)(base + 83886080);
    ushort* wdect = (ushort*)(base + 0);

    embed_kernel<<<NB * WINN, 256, 0, stream>>>(x_input, Wemb, Wlin, h0);

    for (int l = 0; l < NL; ++l) {
        const float* cur = (l == 0) ? h0 : (dec + (long)(l - 1) * 2097152);
        build_x_kernel<<<(NB * TT * HID / 4) / 256, 256, 0, stream>>>(
            pos + (long)l * TT * HID, prev + (long)l * NB * WINN * HID, cur,
            x_f, x_hi, x_lo);

        wsplit4_kernel<<<dim3(32, 32, 4), 256, 0, stream>>>(
            pq + (long)l * HID * HID, pk + (long)l * HID * HID,
            pv + (long)l * HID * HID, pc + (long)l * HID * HID,
            wq_hi, wq_lo, wkv_hi, wkv_lo, wc_hi, wc_lo);
        wsplitff_kernel<<<dim3(128, 32, 2), 256, 0, stream>>>(
            pf1 + (long)l * HID * FFW, pf2 + (long)l * FFW * HID,
            wf1_hi, wf1_lo, wf2_hi, wf2_lo);

        // Fused K+V projection
        hgemm8<<<dim3(2048 / 128, (NB * TT) / 128, 1), 512, 0, stream>>>(
            x_hi, x_lo, wkv_hi, wkv_lo, kv_hi, kv_lo,
            nullptr, nullptr, nullptr, nullptr,
            NB * TT, 2048, HID, HID, 1.f, nullptr, 0, 0);
        // Q projection: split-K4 -> qa..qd (f32); scale folds 1/8 * log2(e)
        hgemm8<<<dim3(HID / 128, (NB * WINN) / 128, 4), 512, 0, stream>>>(
            x_hi, x_lo, wq_hi, wq_lo, nullptr, nullptr, qa, qb, qc, qd,
            NB * WINN, HID, HID, 256, 0.125f * 1.44269504088896f, nullptr, 0, 1);
        vtrans_kernel<<<dim3(HID / 32, (NB * TT) / 32), 256, 0, stream>>>(
            kv_hi + 1024, kv_lo + 1024, vt_hi, vt_lo, 2048);

        fattn_mfma<<<dim3(WINN / 64, NH, NB), 256, 0, stream>>>(
            qa, qb, qc, qd, kv_hi, kv_lo, 2048, vt_hi, vt_lo, o_hi, o_lo);

        // C-proj: split-K4 -> t0a..t0d
        hgemm8<<<dim3(HID / 128, (NB * WINN) / 128, 4), 512, 0, stream>>>(
            o_hi, o_lo, wc_hi, wc_lo, nullptr, nullptr, t0a, t0b, t0c, t0d,
            NB * WINN, HID, HID, 256, 1.f, nullptr, 0, 0);
        ln_res_kernel<<<NB * WINN, 256, 0, stream>>>(
            t0a, t0b, t0c, t0d, x_f, xs, xs_hi, xs_lo, nullptr,
            b1 + l * HID, s1 + l * HID, 1);

        hgemm8<<<dim3(FFW / 128, (NB * WINN) / 128, 1), 512, 0, stream>>>(
            xs_hi, xs_lo, wf1_hi, wf1_lo, ff1_hi, ff1_lo,
            nullptr, nullptr, nullptr, nullptr,
            NB * WINN, FFW, HID, HID, 1.f, bf1 + l * FFW, 1, 0);
        // FF2: split-K4 -> t0a..t0d
        hgemm8<<<dim3(HID / 128, (NB * WINN) / 128, 4), 512, 0, stream>>>(
            ff1_hi, ff1_lo, wf2_hi, wf2_lo, nullptr, nullptr, t0a, t0b, t0c, t0d,
            NB * WINN, HID, FFW, 1024, 1.f, bf2 + l * HID, 0, 0);
        ln_res_kernel<<<NB * WINN, 256, 0, stream>>>(
            t0a, t0b, t0c, t0d, xs, dec + (long)l * 2097152, nullptr, nullptr,
            (l == NL - 1) ? decb : nullptr, b2 + l * HID, s2 + l * HID, 0);
    }

    transp_kernel<<<dim3(VOC / 32, HID / 32), 256, 0, stream>>>(pdec, wdect, HID, VOC);
    mfma_gemm<<<dim3(VOC / 128, (NB * WINN) / 128), 256, 0, stream>>>(
        decb, wdect, logits, NB * WINN, VOC, HID);
}

// Round 14
// 2417.162 us; speedup vs baseline: 1.0057x; 1.0057x over previous
//
#include <hip/hip_runtime.h>
#include <hip/hip_bf16.h>

#define NL   6
#define NH   16
#define HID  1024
#define HD   64
#define FFW  4096
#define VOC  32000
#define WINN 512
#define EMB  128
#define NB   4
#define TT   1024   // WIN + WIN

typedef __attribute__((ext_vector_type(8))) _Float16 f16x8;
typedef __attribute__((ext_vector_type(8))) short    b16x8;
typedef __attribute__((ext_vector_type(4))) float    f32x4;

__device__ __forceinline__ ushort f2b(float f) {
    __hip_bfloat16 h = __float2bfloat16(f);
    return *reinterpret_cast<ushort*>(&h);
}
// split f32 into fp16 hi/lo:  f ~= hi + lo * 2^-11  (error ~ |f|*2^-22)
__device__ __forceinline__ void split16(float f, ushort& hb, ushort& lb) {
    _Float16 h = (_Float16)f;
    _Float16 l = (_Float16)((f - (float)h) * 2048.0f);
    hb = __builtin_bit_cast(ushort, h);
    lb = __builtin_bit_cast(ushort, l);
}
// async global->LDS, 16B per lane: LDS dest = (wave-uniform base) + lane*16
__device__ __forceinline__ void gload16(const void* g, void* l) {
    __builtin_amdgcn_global_load_lds(
        (const __attribute__((address_space(1))) unsigned int*)g,
        (__attribute__((address_space(3))) unsigned int*)l, 16, 0, 0);
}

// ---------------------------------------------------------------------------
// Embed (f32)
// ---------------------------------------------------------------------------
__global__ __launch_bounds__(256) void embed_kernel(
    const int* __restrict__ xin, const float* __restrict__ Wemb,
    const float* __restrict__ Wlin, float* __restrict__ h0)
{
    int row = blockIdx.x;
    int tok = xin[row];
    __shared__ float tk[EMB];
    if (threadIdx.x < EMB) tk[threadIdx.x] = Wemb[tok * EMB + threadIdx.x] * 0.03125f;
    __syncthreads();
    for (int j = 0; j < 4; ++j) {
        int c = threadIdx.x + 256 * j;
        float acc = 0.f;
        for (int e = 0; e < EMB; ++e) acc += tk[e] * Wlin[e * HID + c];
        h0[(long)row * HID + c] = acc;
    }
}

// ---------------------------------------------------------------------------
// x = pos + concat(prev, cur); outputs f32 + fp16 hi/lo split
// ---------------------------------------------------------------------------
__global__ __launch_bounds__(256) void build_x_kernel(
    const float* __restrict__ pos, const float* __restrict__ prev,
    const float* __restrict__ cur, float* __restrict__ x,
    ushort* __restrict__ xh, ushort* __restrict__ xl)
{
    int i4 = blockIdx.x * blockDim.x + threadIdx.x;
    if (i4 >= NB * TT * HID / 4) return;
    int h4 = i4 % (HID / 4);
    int bt = i4 / (HID / 4);
    int t = bt % TT, b = bt / TT;
    float4 p = ((const float4*)pos)[t * (HID / 4) + h4];
    float4 s;
    if (t < WINN) s = ((const float4*)prev)[(long)(b * WINN + t) * (HID / 4) + h4];
    else          s = ((const float4*)cur)[(long)(b * WINN + (t - WINN)) * (HID / 4) + h4];
    float4 r; r.x = p.x + s.x; r.y = p.y + s.y; r.z = p.z + s.z; r.w = p.w + s.w;
    ((float4*)x)[i4] = r;
    ushort4 uh, ul;
    split16(r.x, uh.x, ul.x); split16(r.y, uh.y, ul.y);
    split16(r.z, uh.z, ul.z); split16(r.w, uh.w, ul.w);
    ((ushort4*)xh)[i4] = uh;
    ((ushort4*)xl)[i4] = ul;
}

// ---------------------------------------------------------------------------
// Fused QKVC weight split: z picks {Q,K,V,C}; all 1024x1024.
// ---------------------------------------------------------------------------
__global__ __launch_bounds__(256) void wsplit4_kernel(
    const float* __restrict__ pq, const float* __restrict__ pk,
    const float* __restrict__ pv, const float* __restrict__ pc,
    ushort* __restrict__ wq_h, ushort* __restrict__ wq_l,
    ushort* __restrict__ wkv_h, ushort* __restrict__ wkv_l,
    ushort* __restrict__ wc_h, ushort* __restrict__ wc_l)
{
    const float* src; ushort* dh; ushort* dl;
    switch (blockIdx.z) {
        case 0:  src = pq; dh = wq_h;            dl = wq_l;            break;
        case 1:  src = pk; dh = wkv_h;           dl = wkv_l;           break;
        case 2:  src = pv; dh = wkv_h + 1048576; dl = wkv_l + 1048576; break;
        default: src = pc; dh = wc_h;            dl = wc_l;            break;
    }
    __shared__ float ts[32][33];
    int n0 = blockIdx.x * 32, k0 = blockIdx.y * 32;
    int tr = threadIdx.x >> 5, tc = threadIdx.x & 31;
#pragma unroll
    for (int j = 0; j < 4; ++j)
        ts[tr + j * 8][tc] = src[(long)(k0 + tr + j * 8) * HID + n0 + tc];
    __syncthreads();
#pragma unroll
    for (int j = 0; j < 4; ++j) {
        int n = tr + j * 8;
        ushort hb, lb;
        split16(ts[tc][n], hb, lb);
        long idx = (long)(n0 + n) * HID + k0 + tc;
        dh[idx] = hb;
        dl[idx] = lb;
    }
}

// ---------------------------------------------------------------------------
// Fused FF1+FF2 weight split. grid (128, 32, 2).
// z=0: pf1 [HID,FFW] -> f1 [FFW,HID]; n0=bx*32, k0=by*32
// z=1: pf2 [FFW,HID] -> f2 [HID,FFW]; n0=by*32, k0=bx*32
// ---------------------------------------------------------------------------
__global__ __launch_bounds__(256) void wsplitff_kernel(
    const float* __restrict__ pf1, const float* __restrict__ pf2,
    ushort* __restrict__ f1h, ushort* __restrict__ f1l,
    ushort* __restrict__ f2h, ushort* __restrict__ f2l)
{
    const float* W; ushort* dh; ushort* dl; int K, N, n0, k0;
    if (blockIdx.z == 0) {
        W = pf1; dh = f1h; dl = f1l; K = HID; N = FFW;
        n0 = blockIdx.x * 32; k0 = blockIdx.y * 32;
    } else {
        W = pf2; dh = f2h; dl = f2l; K = FFW; N = HID;
        n0 = blockIdx.y * 32; k0 = blockIdx.x * 32;
    }
    __shared__ float ts[32][33];
    int tr = threadIdx.x >> 5, tc = threadIdx.x & 31;
#pragma unroll
    for (int j = 0; j < 4; ++j)
        ts[tr + j * 8][tc] = W[(long)(k0 + tr + j * 8) * N + n0 + tc];
    __syncthreads();
#pragma unroll
    for (int j = 0; j < 4; ++j) {
        int n = tr + j * 8;
        ushort hb, lb;
        split16(ts[tc][n], hb, lb);
        long idx = (long)(n0 + n) * K + k0 + tc;
        dh[idx] = hb;
        dl[idx] = lb;
    }
}

// ---------------------------------------------------------------------------
// ushort-pair transpose with source row stride
// ---------------------------------------------------------------------------
__global__ __launch_bounds__(256) void vtrans_kernel(
    const ushort* __restrict__ vh, const ushort* __restrict__ vl,
    ushort* __restrict__ vth, ushort* __restrict__ vtl, int src_stride)
{
    __shared__ ushort th[32][33], tl[32][33];
    int n0 = blockIdx.x * 32, r0 = blockIdx.y * 32;
    int tr = threadIdx.x >> 5, tc = threadIdx.x & 31;
#pragma unroll
    for (int j = 0; j < 4; ++j) {
        long g = (long)(r0 + tr + j * 8) * src_stride + n0 + tc;
        th[tr + j * 8][tc] = vh[g];
        tl[tr + j * 8][tc] = vl[g];
    }
    __syncthreads();
#pragma unroll
    for (int j = 0; j < 4; ++j) {
        long g = (long)(n0 + tr + j * 8) * (NB * TT) + r0 + tc;
        vth[g] = th[tc][tr + j * 8];
        vtl[g] = tl[tc][tr + j * 8];
    }
}

// ---------------------------------------------------------------------------
// Unified split-fp16 MFMA GEMM: 128x128 tile, 8 waves (2x4), wave = 64x32,
// BK=32, global_load_lds staging, linear LDS. gridDim.z split-K (k_off=z*Ksub).
// f32 mode (Cf0 != null): block z writes Cf[z], bias only on z==0.
// fp16-split mode: writes Chh/Cll. amap remaps A rows.
// ---------------------------------------------------------------------------
__global__ __launch_bounds__(512) void hgemm8(
    const ushort* __restrict__ Ah, const ushort* __restrict__ Al,
    const ushort* __restrict__ Bh, const ushort* __restrict__ Bl,
    ushort* __restrict__ Chh, ushort* __restrict__ Cll,
    float* __restrict__ Cf0, float* __restrict__ Cf1,
    float* __restrict__ Cf2, float* __restrict__ Cf3,
    int M, int N, int K_stride, int Ksub,
    float scale, const float* __restrict__ bias, int relu, int amap)
{
    __shared__ __align__(16) ushort Ash[128 * 32];
    __shared__ __align__(16) ushort Asl[128 * 32];
    __shared__ __align__(16) ushort Bsh[128 * 32];
    __shared__ __align__(16) ushort Bsl[128 * 32];
    const int tid  = threadIdx.x;
    const int rb   = blockIdx.y * 128;
    const int cb   = blockIdx.x * 128;
    const int z    = blockIdx.z;
    const int k_off = z * Ksub;
    const int wave = tid >> 6, lane = tid & 63;
    const int wr   = (wave >> 2) * 64;
    const int wc   = (wave & 3) * 32;
    const int lr   = lane & 15;
    const int kh   = lane >> 4;

    const int lrow = lane >> 2;
    const int lkc  = (lane & 3) * 8;
    int gra = rb + wave * 16 + lrow;
    long marow = amap ? (long)((gra >> 9) * 1024 + 512 + (gra & 511)) : (long)gra;
    const ushort* gA_h = Ah + marow * K_stride + k_off + lkc;
    const ushort* gA_l = Al + marow * K_stride + k_off + lkc;
    const ushort* gB_h = Bh + (long)(cb + wave * 16 + lrow) * K_stride + k_off + lkc;
    const ushort* gB_l = Bl + (long)(cb + wave * 16 + lrow) * K_stride + k_off + lkc;
    ushort* lA_h = Ash + wave * 512;
    ushort* lA_l = Asl + wave * 512;
    ushort* lB_h = Bsh + wave * 512;
    ushort* lB_l = Bsl + wave * 512;

    int aoff[4], boff[2];
#pragma unroll
    for (int m = 0; m < 4; ++m) aoff[m] = (wr + m * 16 + lr) * 32 + kh * 8;
#pragma unroll
    for (int n = 0; n < 2; ++n) boff[n] = (wc + n * 16 + lr) * 32 + kh * 8;

    f32x4 accH[4][2], accL[4][2];
#pragma unroll
    for (int m = 0; m < 4; ++m)
#pragma unroll
        for (int n = 0; n < 2; ++n) {
            accH[m][n] = (f32x4){0.f, 0.f, 0.f, 0.f};
            accL[m][n] = (f32x4){0.f, 0.f, 0.f, 0.f};
        }

    for (int k0 = 0; k0 < Ksub; k0 += 32) {
        __syncthreads();
        gload16(gA_h + k0, lA_h);
        gload16(gA_l + k0, lA_l);
        gload16(gB_h + k0, lB_h);
        gload16(gB_l + k0, lB_l);
        __syncthreads();
        f16x8 afh[4], afl[4], bfh[2], bfl[2];
#pragma unroll
        for (int m = 0; m < 4; ++m) {
            afh[m] = *(const f16x8*)(Ash + aoff[m]);
            afl[m] = *(const f16x8*)(Asl + aoff[m]);
        }
#pragma unroll
        for (int n = 0; n < 2; ++n) {
            bfh[n] = *(const f16x8*)(Bsh + boff[n]);
            bfl[n] = *(const f16x8*)(Bsl + boff[n]);
        }
#pragma unroll
        for (int m = 0; m < 4; ++m)
#pragma unroll
            for (int n = 0; n < 2; ++n) {
                accH[m][n] = __builtin_amdgcn_mfma_f32_16x16x32_f16(afh[m], bfh[n], accH[m][n], 0, 0, 0);
                accL[m][n] = __builtin_amdgcn_mfma_f32_16x16x32_f16(afh[m], bfl[n], accL[m][n], 0, 0, 0);
                accL[m][n] = __builtin_amdgcn_mfma_f32_16x16x32_f16(afl[m], bfh[n], accL[m][n], 0, 0, 0);
            }
    }

    if (Cf0) {
        float* __restrict__ Cf = (z == 0) ? Cf0 : (z == 1) ? Cf1 : (z == 2) ? Cf2 : Cf3;
        const float* bias_eff = (z == 0) ? bias : nullptr;
#pragma unroll
        for (int m = 0; m < 4; ++m) {
            int row0 = rb + wr + m * 16 + kh * 4;
#pragma unroll
            for (int n = 0; n < 2; ++n) {
                int col = cb + wc + n * 16 + lr;
                float bv = bias_eff ? bias_eff[col] : 0.f;
#pragma unroll
                for (int r = 0; r < 4; ++r) {
                    float v = (accH[m][n][r] + accL[m][n][r] * (1.f / 2048.f)) * scale + bv;
                    if (relu) v = fmaxf(v, 0.f);
                    Cf[(long)(row0 + r) * N + col] = v;
                }
            }
        }
    } else {
#pragma unroll
        for (int m = 0; m < 4; ++m) {
            int row0 = rb + wr + m * 16 + kh * 4;
#pragma unroll
            for (int n = 0; n < 2; ++n) {
                int col = cb + wc + n * 16 + lr;
                float bv = bias ? bias[col] : 0.f;
#pragma unroll
                for (int r = 0; r < 4; ++r) {
                    float v = (accH[m][n][r] + accL[m][n][r] * (1.f / 2048.f)) * scale + bv;
                    if (relu) v = fmaxf(v, 0.f);
                    long idx = (long)(row0 + r) * N + col;
                    ushort hb, lb; split16(v, hb, lb);
                    Chh[idx] = hb; Cll[idx] = lb;
                }
            }
        }
    }
}

// ---------------------------------------------------------------------------
// MFMA flash attention with T14 async-STAGE. Q = qa+qb+qc+qd (f32 partials).
// (R12 version — the R13 softmax variants regressed and were reverted.)
// ---------------------------------------------------------------------------
__global__ __launch_bounds__(256) void fattn_mfma(
    const float* __restrict__ qa, const float* __restrict__ qb,
    const float* __restrict__ qc, const float* __restrict__ qd,
    const ushort* __restrict__ kbh, const ushort* __restrict__ kbl, int kstr,
    const ushort* __restrict__ vth, const ushort* __restrict__ vtl,
    ushort* __restrict__ oh, ushort* __restrict__ ol)
{
    __shared__ __align__(16) ushort ksh[64 * 72];
    __shared__ __align__(16) ushort ksl[64 * 72];
    __shared__ __align__(16) ushort vsh[64 * 72];
    __shared__ __align__(16) ushort vsl[64 * 72];
    const int qt = blockIdx.x, h = blockIdx.y, b = blockIdx.z;
    const int tid = threadIdx.x;
    const int wave = tid >> 6, lane = tid & 63;
    const int lr = lane & 15, kg4 = lane >> 4;
    const int qbase = b * WINN + qt * 64;

    f16x8 qfh[2], qfl[2];
#pragma unroll
    for (int c = 0; c < 2; ++c) {
        long ga = (long)(qbase + wave * 16 + lr) * HID + h * HD + c * 32 + kg4 * 8;
        float4 a0 = *(const float4*)(qa + ga);
        float4 a1 = *(const float4*)(qa + ga + 4);
        float4 b0 = *(const float4*)(qb + ga);
        float4 b1 = *(const float4*)(qb + ga + 4);
        float4 c0 = *(const float4*)(qc + ga);
        float4 c1 = *(const float4*)(qc + ga + 4);
        float4 d0 = *(const float4*)(qd + ga);
        float4 d1 = *(const float4*)(qd + ga + 4);
        float qv[8] = {a0.x + b0.x + c0.x + d0.x, a0.y + b0.y + c0.y + d0.y,
                       a0.z + b0.z + c0.z + d0.z, a0.w + b0.w + c0.w + d0.w,
                       a1.x + b1.x + c1.x + d1.x, a1.y + b1.y + c1.y + d1.y,
                       a1.z + b1.z + c1.z + d1.z, a1.w + b1.w + c1.w + d1.w};
        ushort uh[8], ul[8];
#pragma unroll
        for (int j = 0; j < 8; ++j) split16(qv[j], uh[j], ul[j]);
        qfh[c] = *(const f16x8*)uh;
        qfl[c] = *(const f16x8*)ul;
    }

    f32x4 accOH[4], accOL[4];
#pragma unroll
    for (int d = 0; d < 4; ++d) {
        accOH[d] = (f32x4){0.f, 0.f, 0.f, 0.f};
        accOL[d] = (f32x4){0.f, 0.f, 0.f, 0.f};
    }
    float mrow[4], lrow[4];
#pragma unroll
    for (int r = 0; r < 4; ++r) { mrow[r] = -3.0e38f; lrow[r] = 0.f; }

    const int sr = tid >> 2;
    const int sd = (tid & 3) * 16;

    uint4 rk0, rk1, rk2, rk3, rv0, rv1, rv2, rv3;
    {   // prologue: tile 0 -> regs
        long gk = (long)(b * TT + sr) * kstr + h * HD + sd;
        rk0 = *(const uint4*)(kbh + gk); rk1 = *(const uint4*)(kbh + gk + 8);
        rk2 = *(const uint4*)(kbl + gk); rk3 = *(const uint4*)(kbl + gk + 8);
        long gv = (long)(h * HD + sr) * (NB * TT) + b * TT + sd;
        rv0 = *(const uint4*)(vth + gv); rv1 = *(const uint4*)(vth + gv + 8);
        rv2 = *(const uint4*)(vtl + gv); rv3 = *(const uint4*)(vtl + gv + 8);
    }

    const int ktmax = 9 + qt;
    for (int kt = 0; kt < ktmax; ++kt) {
        __syncthreads();
        *(uint4*)(ksh + sr * 72 + sd) = rk0;
        *(uint4*)(ksh + sr * 72 + sd + 8) = rk1;
        *(uint4*)(ksl + sr * 72 + sd) = rk2;
        *(uint4*)(ksl + sr * 72 + sd + 8) = rk3;
        *(uint4*)(vsh + sr * 72 + sd) = rv0;
        *(uint4*)(vsh + sr * 72 + sd + 8) = rv1;
        *(uint4*)(vsl + sr * 72 + sd) = rv2;
        *(uint4*)(vsl + sr * 72 + sd + 8) = rv3;
        __syncthreads();

        f32x4 sH[4], sL[4];
#pragma unroll
        for (int n = 0; n < 4; ++n) {
            sH[n] = (f32x4){0.f, 0.f, 0.f, 0.f};
            sL[n] = (f32x4){0.f, 0.f, 0.f, 0.f};
        }
#pragma unroll
        for (int c = 0; c < 2; ++c) {
#pragma unroll
            for (int n = 0; n < 4; ++n) {
                int ad = (n * 16 + lr) * 72 + c * 32 + kg4 * 8;
                f16x8 bh = *(const f16x8*)(ksh + ad);
                f16x8 bl = *(const f16x8*)(ksl + ad);
                sH[n] = __builtin_amdgcn_mfma_f32_16x16x32_f16(qfh[c], bh, sH[n], 0, 0, 0);
                sL[n] = __builtin_amdgcn_mfma_f32_16x16x32_f16(qfh[c], bl, sL[n], 0, 0, 0);
                sL[n] = __builtin_amdgcn_mfma_f32_16x16x32_f16(qfl[c], bh, sL[n], 0, 0, 0);
            }
        }

        // T14: next tile's global loads issue here; latency hides under
        // softmax + PV.
        if (kt + 1 < ktmax) {
            long gk = (long)(b * TT + (kt + 1) * 64 + sr) * kstr + h * HD + sd;
            rk0 = *(const uint4*)(kbh + gk); rk1 = *(const uint4*)(kbh + gk + 8);
            rk2 = *(const uint4*)(kbl + gk); rk3 = *(const uint4*)(kbl + gk + 8);
            long gv = (long)(h * HD + sr) * (NB * TT) + b * TT + (kt + 1) * 64 + sd;
            rv0 = *(const uint4*)(vth + gv); rv1 = *(const uint4*)(vth + gv + 8);
            rv2 = *(const uint4*)(vtl + gv); rv3 = *(const uint4*)(vtl + gv + 8);
        }

        float S[4][4];
#pragma unroll
        for (int n = 0; n < 4; ++n)
#pragma unroll
            for (int r = 0; r < 4; ++r)
                S[n][r] = sH[n][r] + sL[n][r] * (1.f / 2048.f);

        if (kt == ktmax - 1) {
#pragma unroll
            for (int r = 0; r < 4; ++r) {
                int qi = WINN + qt * 64 + wave * 16 + kg4 * 4 + r;
#pragma unroll
                for (int n = 0; n < 4; ++n) {
                    int kg = kt * 64 + n * 16 + lr;
                    if (kg > qi) S[n][r] = -1e9f;
                }
            }
        }

#pragma unroll
        for (int r = 0; r < 4; ++r) {
            float mx = fmaxf(fmaxf(S[0][r], S[1][r]), fmaxf(S[2][r], S[3][r]));
            mx = fmaxf(mx, __shfl_xor(mx, 1));
            mx = fmaxf(mx, __shfl_xor(mx, 2));
            mx = fmaxf(mx, __shfl_xor(mx, 4));
            mx = fmaxf(mx, __shfl_xor(mx, 8));
            float mnew = fmaxf(mrow[r], mx);
            float alpha = __expf(mrow[r] - mnew);
            float rs = 0.f;
#pragma unroll
            for (int n = 0; n < 4; ++n) { S[n][r] = __expf(S[n][r] - mnew); rs += S[n][r]; }
            rs += __shfl_xor(rs, 1);
            rs += __shfl_xor(rs, 2);
            rs += __shfl_xor(rs, 4);
            rs += __shfl_xor(rs, 8);
            lrow[r] = lrow[r] * alpha + rs;
            mrow[r] = mnew;
#pragma unroll
            for (int d = 0; d < 4; ++d) { accOH[d][r] *= alpha; accOL[d][r] *= alpha; }
        }

        __syncthreads();
#pragma unroll
        for (int n = 0; n < 4; ++n)
#pragma unroll
            for (int r = 0; r < 4; ++r) {
                ushort hb, lb;
                split16(S[n][r], hb, lb);
                int ad = (wave * 16 + kg4 * 4 + r) * 72 + n * 16 + lr;
                ksh[ad] = hb;
                ksl[ad] = lb;
            }
        f16x8 pfh[2], pfl[2];
#pragma unroll
        for (int c = 0; c < 2; ++c) {
            int ad = (wave * 16 + lr) * 72 + c * 32 + kg4 * 8;
            pfh[c] = *(const f16x8*)(ksh + ad);
            pfl[c] = *(const f16x8*)(ksl + ad);
        }
#pragma unroll
        for (int c = 0; c < 2; ++c) {
#pragma unroll
            for (int d = 0; d < 4; ++d) {
                int ad = (d * 16 + lr) * 72 + c * 32 + kg4 * 8;
                f16x8 vh = *(const f16x8*)(vsh + ad);
                f16x8 vl = *(const f16x8*)(vsl + ad);
                accOH[d] = __builtin_amdgcn_mfma_f32_16x16x32_f16(pfh[c], vh, accOH[d], 0, 0, 0);
                accOL[d] = __builtin_amdgcn_mfma_f32_16x16x32_f16(pfh[c], vl, accOL[d], 0, 0, 0);
                accOL[d] = __builtin_amdgcn_mfma_f32_16x16x32_f16(pfl[c], vh, accOL[d], 0, 0, 0);
            }
        }
    }

#pragma unroll
    for (int r = 0; r < 4; ++r) {
        float inv = 1.f / lrow[r];
        long rowb = (long)(qbase + wave * 16 + kg4 * 4 + r) * HID + h * HD + lr;
#pragma unroll
        for (int d = 0; d < 4; ++d) {
            float v = (accOH[d][r] + accOL[d][r] * (1.f / 2048.f)) * inv;
            ushort hb, lb;
            split16(v, hb, lb);
            oh[rowb + d * 16] = hb;
            ol[rowb + d * 16] = lb;
        }
    }
}

// ---------------------------------------------------------------------------
// Transpose+convert (bf16, logits W)
// ---------------------------------------------------------------------------
__global__ __launch_bounds__(256) void transp_kernel(
    const float* __restrict__ W, ushort* __restrict__ Wt, int K, int N)
{
    __shared__ float ts[32][33];
    int n0 = blockIdx.x * 32, k0 = blockIdx.y * 32;
    int tr = threadIdx.x >> 5, tc = threadIdx.x & 31;
#pragma unroll
    for (int j = 0; j < 4; ++j)
        ts[tr + j * 8][tc] = W[(long)(k0 + tr + j * 8) * N + n0 + tc];
    __syncthreads();
#pragma unroll
    for (int j = 0; j < 4; ++j) {
        int n = tr + j * 8;
        Wt[(long)(n0 + n) * K + k0 + tc] = f2b(ts[tc][n]);
    }
}

// ---------------------------------------------------------------------------
// bf16 MFMA GEMM (logits). B-reuse-ordered XCD swizzle + global_load_lds.
// ---------------------------------------------------------------------------
__global__ __launch_bounds__(256) void mfma_gemm(
    const ushort* __restrict__ A, const ushort* __restrict__ Bt,
    float* __restrict__ Cf, int M, int N, int K)
{
    __shared__ __align__(16) ushort As[128 * 32];
    __shared__ __align__(16) ushort Bs[128 * 32];
    const int tid  = threadIdx.x;
    const int ntm  = M >> 7;
    const int nbx  = gridDim.x;
    const int nwg  = nbx * gridDim.y;
    const int bid  = blockIdx.y * nbx + blockIdx.x;
    const int cpx  = nwg >> 3;
    const int swz  = (bid & 7) * cpx + (bid >> 3);
    const int rb   = (swz % ntm) * 128;
    const int cb   = (swz / ntm) * 128;
    const int wave = tid >> 6, lane = tid & 63;
    const int wr   = (wave >> 1) * 64;
    const int wc   = (wave & 1) * 64;
    const int lr   = lane & 15;
    const int kh   = lane >> 4;

    const int lrow = lane >> 2;
    const int lkc  = (lane & 3) * 8;
    const ushort* gA0 = A + (long)(rb + wave * 32 + lrow) * K + lkc;
    const ushort* gA1 = A + (long)(rb + wave * 32 + 16 + lrow) * K + lkc;
    const ushort* gB0 = Bt + (long)(cb + wave * 32 + lrow) * K + lkc;
    const ushort* gB1 = Bt + (long)(cb + wave * 32 + 16 + lrow) * K + lkc;
    ushort* lA0 = As + wave * 1024;
    ushort* lA1 = As + wave * 1024 + 512;
    ushort* lB0 = Bs + wave * 1024;
    ushort* lB1 = Bs + wave * 1024 + 512;

    int aoff[4], boff[4];
#pragma unroll
    for (int m = 0; m < 4; ++m) aoff[m] = (wr + m * 16 + lr) * 32 + kh * 8;
#pragma unroll
    for (int n = 0; n < 4; ++n) boff[n] = (wc + n * 16 + lr) * 32 + kh * 8;

    f32x4 acc[4][4];
#pragma unroll
    for (int m = 0; m < 4; ++m)
#pragma unroll
        for (int n = 0; n < 4; ++n)
            acc[m][n] = (f32x4){0.f, 0.f, 0.f, 0.f};

    for (int k0 = 0; k0 < K; k0 += 32) {
        __syncthreads();
        gload16(gA0 + k0, lA0);
        gload16(gA1 + k0, lA1);
        gload16(gB0 + k0, lB0);
        gload16(gB1 + k0, lB1);
        __syncthreads();
        b16x8 af[4], bfr[4];
#pragma unroll
        for (int m = 0; m < 4; ++m) af[m] = *(const b16x8*)(As + aoff[m]);
#pragma unroll
        for (int n = 0; n < 4; ++n) bfr[n] = *(const b16x8*)(Bs + boff[n]);
#pragma unroll
        for (int m = 0; m < 4; ++m)
#pragma unroll
            for (int n = 0; n < 4; ++n)
                acc[m][n] = __builtin_amdgcn_mfma_f32_16x16x32_bf16(af[m], bfr[n], acc[m][n], 0, 0, 0);
    }

#pragma unroll
    for (int m = 0; m < 4; ++m) {
        int row0 = rb + wr + m * 16 + kh * 4;
#pragma unroll
        for (int n = 0; n < 4; ++n) {
            int col = cb + wc + n * 16 + lr;
#pragma unroll
            for (int r = 0; r < 4; ++r)
                Cf[(long)(row0 + r) * N + col] = acc[m][n][r];
        }
    }
}

// ---------------------------------------------------------------------------
// out = res[r'] + LN(t + t2 + t3 + t4)*scale + bias (t2..t4 optional);
// outputs f32 / fp16-split / bf16 mirrors.
// ---------------------------------------------------------------------------
__global__ __launch_bounds__(256) void ln_res_kernel(
    const float* __restrict__ t, const float* __restrict__ t2,
    const float* __restrict__ t3, const float* __restrict__ t4,
    const float* __restrict__ res, float* __restrict__ out,
    ushort* __restrict__ outh, ushort* __restrict__ outl, ushort* __restrict__ outb,
    const float* __restrict__ bias, const float* __restrict__ scale, int res_map)
{
    int r = blockIdx.x;
    int tid = threadIdx.x;
    long rr = res_map ? (long)((r >> 9) * 1024 + 512 + (r & 511)) : (long)r;
    float4 v = ((const float4*)(t + (long)r * HID))[tid];
    if (t2) {
        float4 w = ((const float4*)(t2 + (long)r * HID))[tid];
        v.x += w.x; v.y += w.y; v.z += w.z; v.w += w.w;
    }
    if (t3) {
        float4 w = ((const float4*)(t3 + (long)r * HID))[tid];
        v.x += w.x; v.y += w.y; v.z += w.z; v.w += w.w;
    }
    if (t4) {
        float4 w = ((const float4*)(t4 + (long)r * HID))[tid];
        v.x += w.x; v.y += w.y; v.z += w.z; v.w += w.w;
    }
    __shared__ float red[4];
    float s = v.x + v.y + v.z + v.w;
    for (int off = 32; off > 0; off >>= 1) s += __shfl_xor(s, off);
    if ((tid & 63) == 0) red[tid >> 6] = s;
    __syncthreads();
    float mean = (red[0] + red[1] + red[2] + red[3]) * (1.f / HID);
    __syncthreads();
    float dx = v.x - mean, dy = v.y - mean, dz = v.z - mean, dw = v.w - mean;
    float qs = dx * dx + dy * dy + dz * dz + dw * dw;
    for (int off = 32; off > 0; off >>= 1) qs += __shfl_xor(qs, off);
    if ((tid & 63) == 0) red[tid >> 6] = qs;
    __syncthreads();
    float var = (red[0] + red[1] + red[2] + red[3]) * (1.f / HID);
    float rs = rsqrtf(var + 1e-6f);
    float4 rv = ((const float4*)(res + rr * HID))[tid];
    float4 sc4 = ((const float4*)scale)[tid];
    float4 b4  = ((const float4*)bias)[tid];
    float4 o4;
    o4.x = rv.x + dx * rs * sc4.x + b4.x;
    o4.y = rv.y + dy * rs * sc4.y + b4.y;
    o4.z = rv.z + dz * rs * sc4.z + b4.z;
    o4.w = rv.w + dw * rs * sc4.w + b4.w;
    ((float4*)(out + (long)r * HID))[tid] = o4;
    if (outh) {
        ushort4 uh, ul;
        split16(o4.x, uh.x, ul.x); split16(o4.y, uh.y, ul.y);
        split16(o4.z, uh.z, ul.z); split16(o4.w, uh.w, ul.w);
        ((ushort4*)(outh + (long)r * HID))[tid] = uh;
        ((ushort4*)(outl + (long)r * HID))[tid] = ul;
    }
    if (outb) {
        ushort4 u; u.x = f2b(o4.x); u.y = f2b(o4.y); u.z = f2b(o4.z); u.w = f2b(o4.w);
        ((ushort4*)(outb + (long)r * HID))[tid] = u;
    }
}

// ---------------------------------------------------------------------------
// Workspace (168 MiB, proven safe). Overlays as R12.
// ---------------------------------------------------------------------------
extern "C" void kernel_launch(void* const* d_in, const int* in_sizes, int n_in,
                              void* d_out, int out_size, void* d_ws, size_t ws_size,
                              hipStream_t stream)
{
    const int*   x_input = (const int*)  d_in[0];
    const float* prev    = (const float*)d_in[1];
    const float* Wemb    = (const float*)d_in[2];
    const float* Wlin    = (const float*)d_in[3];
    const float* pdec    = (const float*)d_in[4];
    const float* pq      = (const float*)d_in[5];
    const float* pk      = (const float*)d_in[6];
    const float* pv      = (const float*)d_in[7];
    const float* pc      = (const float*)d_in[8];
    const float* pf1     = (const float*)d_in[9];
    const float* pf2     = (const float*)d_in[10];
    const float* bf1     = (const float*)d_in[11];
    const float* bf2     = (const float*)d_in[12];
    const float* b1      = (const float*)d_in[13];
    const float* b2      = (const float*)d_in[14];
    const float* s1      = (const float*)d_in[15];
    const float* s2      = (const float*)d_in[16];
    const float* pos     = (const float*)d_in[17];

    float* outp   = (float*)d_out;
    float* logits = outp;
    float* dec    = outp + (long)2048 * VOC;

    char* base = (char*)d_ws;
    float*  x_f   = (float*) (base + 0);
    ushort* x_hi  = (ushort*)(base + 16777216);
    ushort* x_lo  = (ushort*)(base + 25165824);
    ushort* kv_hi = (ushort*)(base + 33554432);
    ushort* kv_lo = (ushort*)(base + 50331648);
    ushort* vt_hi = (ushort*)(base + 67108864);
    ushort* vt_lo = (ushort*)(base + 75497472);
    ushort* o_hi  = (ushort*)(base + 83886080);
    ushort* o_lo  = (ushort*)(base + 88080384);
    float*  t0a   = (float*) (base + 92274688);
    float*  h0    = t0a;
    float*  qa    = t0a;
    float*  t0b   = (float*) (base + 100663296);
    float*  qb    = t0b;
    float*  xs    = (float*) (base + 109051904);
    ushort* xs_hi = (ushort*)(base + 117440512);
    ushort* xs_lo = (ushort*)(base + 121634816);
    ushort* wq_hi = (ushort*)(base + 125829120);
    ushort* wq_lo = (ushort*)(base + 127926272);
    ushort* wkv_hi= (ushort*)(base + 130023424);
    ushort* wkv_lo= (ushort*)(base + 134217728);
    ushort* wc_hi = (ushort*)(base + 138412032);
    ushort* wc_lo = (ushort*)(base + 140509184);
    ushort* wf1_hi= (ushort*)(base + 142606336);
    ushort* wf1_lo= (ushort*)(base + 150994944);
    ushort* wf2_hi= (ushort*)(base + 159383552);
    ushort* wf2_lo= (ushort*)(base + 167772160);   // ends 176,160,768
    // overlays
    float*  t0c   = (float*) (base + 67108864);    // vt_hi region (post-fattn)
    float*  t0d   = (float*) (base + 75497472);    // vt_lo region (post-fattn)
    float*  qc    = (float*) (base + 109051904);   // xs region (pre-ln1)
    float*  qd    = (float*) (base + 117440512);   // xs_hi+xs_lo region (pre-ln1)
    ushort* ff1_hi= (ushort*)(base + 33554432);
    ushort* ff1_lo= (ushort*)(base + 50331648);
    ushort* decb  = (ushort*)(base + 83886080);
    ushort* wdect = (ushort*)(base + 0);

    embed_kernel<<<NB * WINN, 256, 0, stream>>>(x_input, Wemb, Wlin, h0);

    for (int l = 0; l < NL; ++l) {
        const float* cur = (l == 0) ? h0 : (dec + (long)(l - 1) * 2097152);
        build_x_kernel<<<(NB * TT * HID / 4) / 256, 256, 0, stream>>>(
            pos + (long)l * TT * HID, prev + (long)l * NB * WINN * HID, cur,
            x_f, x_hi, x_lo);

        wsplit4_kernel<<<dim3(32, 32, 4), 256, 0, stream>>>(
            pq + (long)l * HID * HID, pk + (long)l * HID * HID,
            pv + (long)l * HID * HID, pc + (long)l * HID * HID,
            wq_hi, wq_lo, wkv_hi, wkv_lo, wc_hi, wc_lo);
        wsplitff_kernel<<<dim3(128, 32, 2), 256, 0, stream>>>(
            pf1 + (long)l * HID * FFW, pf2 + (long)l * FFW * HID,
            wf1_hi, wf1_lo, wf2_hi, wf2_lo);

        // Fused K+V projection
        hgemm8<<<dim3(2048 / 128, (NB * TT) / 128, 1), 512, 0, stream>>>(
            x_hi, x_lo, wkv_hi, wkv_lo, kv_hi, kv_lo,
            nullptr, nullptr, nullptr, nullptr,
            NB * TT, 2048, HID, HID, 1.f, nullptr, 0, 0);
        // Q projection: split-K4 -> qa..qd (f32)
        hgemm8<<<dim3(HID / 128, (NB * WINN) / 128, 4), 512, 0, stream>>>(
            x_hi, x_lo, wq_hi, wq_lo, nullptr, nullptr, qa, qb, qc, qd,
            NB * WINN, HID, HID, 256, 0.125f, nullptr, 0, 1);
        vtrans_kernel<<<dim3(HID / 32, (NB * TT) / 32), 256, 0, stream>>>(
            kv_hi + 1024, kv_lo + 1024, vt_hi, vt_lo, 2048);

        fattn_mfma<<<dim3(WINN / 64, NH, NB), 256, 0, stream>>>(
            qa, qb, qc, qd, kv_hi, kv_lo, 2048, vt_hi, vt_lo, o_hi, o_lo);

        // C-proj: split-K4 -> t0a..t0d
        hgemm8<<<dim3(HID / 128, (NB * WINN) / 128, 4), 512, 0, stream>>>(
            o_hi, o_lo, wc_hi, wc_lo, nullptr, nullptr, t0a, t0b, t0c, t0d,
            NB * WINN, HID, HID, 256, 1.f, nullptr, 0, 0);
        ln_res_kernel<<<NB * WINN, 256, 0, stream>>>(
            t0a, t0b, t0c, t0d, x_f, xs, xs_hi, xs_lo, nullptr,
            b1 + l * HID, s1 + l * HID, 1);

        hgemm8<<<dim3(FFW / 128, (NB * WINN) / 128, 1), 512, 0, stream>>>(
            xs_hi, xs_lo, wf1_hi, wf1_lo, ff1_hi, ff1_lo,
            nullptr, nullptr, nullptr, nullptr,
            NB * WINN, FFW, HID, HID, 1.f, bf1 + l * FFW, 1, 0);
        // FF2: split-K4 -> t0a..t0d
        hgemm8<<<dim3(HID / 128, (NB * WINN) / 128, 4), 512, 0, stream>>>(
            ff1_hi, ff1_lo, wf2_hi, wf2_lo, nullptr, nullptr, t0a, t0b, t0c, t0d,
            NB * WINN, HID, FFW, 1024, 1.f, bf2 + l * HID, 0, 0);
        ln_res_kernel<<<NB * WINN, 256, 0, stream>>>(
            t0a, t0b, t0c, t0d, xs, dec + (long)l * 2097152, nullptr, nullptr,
            (l == NL - 1) ? decb : nullptr, b2 + l * HID, s2 + l * HID, 0);
    }

    transp_kernel<<<dim3(VOC / 32, HID / 32), 256, 0, stream>>>(pdec, wdect, HID, VOC);
    mfma_gemm<<<dim3(VOC / 128, (NB * WINN) / 128), 256, 0, stream>>>(
        decb, wdect, logits, NB * WINN, VOC, HID);
}